// Round 8
// baseline (749.645 us; speedup 1.0000x reference)
//
#include <hip/hip_runtime.h>
#include <cmath>

#define B_ 2
#define T_ 4096
#define C_ 2048
#define H_ 32
#define N_ 64
#define L_ 64
#define NC_ 64
#define BT_ 8192

typedef unsigned short u16;
typedef unsigned int u32;
typedef __attribute__((ext_vector_type(8))) short bf16x8;
typedef __attribute__((ext_vector_type(4))) float f32x4;

// ---------- storage abstraction: fp32 or bf16-in-memory (compute fp32) ----------
template <typename T> struct io;
template <> struct io<float> {
  static __device__ __forceinline__ float  ld (const float* p) { return *p; }
  static __device__ __forceinline__ float4 ld4(const float* p) { return *(const float4*)p; }
  static __device__ __forceinline__ void st (float* p, float v) { *p = v; }
  static __device__ __forceinline__ void st4(float* p, float4 v) { *(float4*)p = v; }
};
template <> struct io<u16> {
  static __device__ __forceinline__ float ld(const u16* p) {
    return __uint_as_float((unsigned)(*p) << 16);
  }
  static __device__ __forceinline__ float4 ld4(const u16* p) {
    ushort4 u = *(const ushort4*)p;
    return make_float4(__uint_as_float((unsigned)u.x << 16),
                       __uint_as_float((unsigned)u.y << 16),
                       __uint_as_float((unsigned)u.z << 16),
                       __uint_as_float((unsigned)u.w << 16));
  }
  static __device__ __forceinline__ u16 cvt1(float x) {
    unsigned u = __float_as_uint(x);
    return (u16)((u + 0x7fffu + ((u >> 16) & 1u)) >> 16);
  }
  static __device__ __forceinline__ void st(u16* p, float v) { *p = cvt1(v); }
  static __device__ __forceinline__ void st4(u16* p, float4 v) {
    ushort4 u;
    u.x = cvt1(v.x); u.y = cvt1(v.y); u.z = cvt1(v.z); u.w = cvt1(v.w);
    *(ushort4*)p = u;
  }
};

// broadcast lane `lane`'s value of v to all lanes (v_readlane)
static __device__ __forceinline__ float bcast(float v, int lane) {
  return __uint_as_float(__builtin_amdgcn_readlane(__float_as_uint(v), lane));
}
static __device__ __forceinline__ u32 bcast_u(u32 v, int lane) {
  return (u32)__builtin_amdgcn_readlane((int)v, lane);
}
// bf16-pair unpack; on a uniform (readlane) value these lower to s_lshl/s_and (SALU)
static __device__ __forceinline__ float bflo(u32 u) { return __uint_as_float(u << 16); }
static __device__ __forceinline__ float bfhi(u32 u) { return __uint_as_float(u & 0xffff0000u); }

// ---------------- K0: Z = x + (shift(x) - x) * maa_x ----------------
template <typename ST>
static __global__ __launch_bounds__(256) void k0_z(
    const float* __restrict__ hidden, const float* __restrict__ attn_x,
    const float* __restrict__ maa_x, ST* __restrict__ Z) {
  int idx = blockIdx.x * 256 + threadIdx.x;
  int base = idx * 4;
  int bt = base >> 11;           // / C_
  int c  = base & (C_ - 1);
  int t  = bt & (T_ - 1);
  int b  = bt >> 12;
  float4 x = *(const float4*)(hidden + (size_t)base);
  float4 xp;
  if (t == 0) xp = *(const float4*)(attn_x + (size_t)b * C_ + c);
  else        xp = *(const float4*)(hidden + (size_t)base - C_);
  float4 mx = *(const float4*)(maa_x + c);
  float4 z;
  z.x = x.x + (xp.x - x.x) * mx.x;
  z.y = x.y + (xp.y - x.y) * mx.y;
  z.z = x.z + (xp.z - x.z) * mx.z;
  z.w = x.w + (xp.w - x.w) * mx.w;
  io<ST>::st4(Z + (size_t)base, z);
}

// ---------------- WT: transpose+convert weights to bf16 ----------------
static __global__ __launch_bounds__(256) void wt_prep(
    const float* __restrict__ W1, const float* __restrict__ DW1,
    u16* __restrict__ W1T, u16* __restrict__ DW1T) {
  __shared__ u16 tile[64][65];
  int blk = blockIdx.x;
  const float* src; u16* dst; int c0, j0, srcld;
  if (blk < 64) { src = W1;  dst = W1T;  c0 = (blk >> 1) * 64; j0 = (blk & 1) * 64; srcld = 160; }
  else          { src = DW1; dst = DW1T; c0 = (blk - 64) * 64; j0 = 0;              srcld = 64;  }
  int tid = threadIdx.x;
  int jj = tid & 63, cr = tid >> 6;
#pragma unroll
  for (int i = 0; i < 16; ++i) {
    int c = cr + i * 4;
    tile[c][jj] = io<u16>::cvt1(src[(size_t)(c0 + c) * srcld + j0 + jj]);
  }
  __syncthreads();
  int cw = tid & 63, jr = tid >> 6;
#pragma unroll
  for (int i = 0; i < 16; ++i) {
    int j = jr + i * 4;
    dst[(size_t)(j0 + j) * 2048 + c0 + cw] = tile[cw][j];
  }
}

// ---------------- K1 (bf16, MFMA): P = tanh(Z @ W1) ----------------
static __global__ __launch_bounds__(256) void k1_mfma(
    const u16* __restrict__ Z, const u16* __restrict__ W1T,
    float* __restrict__ P) {
  int tid = threadIdx.x;
  int lane = tid & 63, wv = tid >> 6;
  int bt0 = blockIdx.x * 16;
  int j0 = wv * 32;
  int row = lane & 15, kg = lane >> 4;
  const u16* za  = Z   + (size_t)(bt0 + row) * C_ + kg * 8;
  const u16* b0p = W1T + (size_t)(j0 + row) * C_ + kg * 8;
  const u16* b1p = W1T + (size_t)(j0 + 16 + row) * C_ + kg * 8;
  f32x4 acc0 = {0.f, 0.f, 0.f, 0.f}, acc1 = {0.f, 0.f, 0.f, 0.f};
#pragma unroll 8
  for (int c0 = 0; c0 < C_; c0 += 32) {
    bf16x8 a  = *(const bf16x8*)(za + c0);
    bf16x8 b0 = *(const bf16x8*)(b0p + c0);
    bf16x8 b1 = *(const bf16x8*)(b1p + c0);
    acc0 = __builtin_amdgcn_mfma_f32_16x16x32_bf16(a, b0, acc0, 0, 0, 0);
    acc1 = __builtin_amdgcn_mfma_f32_16x16x32_bf16(a, b1, acc1, 0, 0, 0);
  }
  int orow = bt0 + kg * 4;
  int ocol = row;
#pragma unroll
  for (int rg = 0; rg < 4; ++rg) {
    P[(size_t)(orow + rg) * 128 + j0 + ocol]      = tanhf(acc0[rg]);
    P[(size_t)(orow + rg) * 128 + j0 + 16 + ocol] = tanhf(acc1[rg]);
  }
}

// ---------------- K1 (fp32 legacy): readlane-broadcast GEMM ----------------
template <typename ST>
static __global__ __launch_bounds__(256) void k1_p(
    const ST* __restrict__ Z, const float* __restrict__ W1,
    float* __restrict__ P) {
  __shared__ float w1s[2][64 * 128];
  int tid = threadIdx.x;
  int lane = tid & 63;
  int wv = tid >> 6;
  int bt0 = blockIdx.x * 16 + wv * 4;
  float acc[4][2];
#pragma unroll
  for (int tk = 0; tk < 4; ++tk) { acc[tk][0] = 0.f; acc[tk][1] = 0.f; }

#pragma unroll
  for (int q = 0; q < 8; ++q) {
    int idx = q * 256 + tid;
    int cc = idx >> 5;
    int j4 = (idx & 31) * 4;
    *(float4*)&w1s[0][cc * 128 + j4] = *(const float4*)&W1[(size_t)cc * 160 + j4];
  }
  __syncthreads();

#pragma unroll 1
  for (int ch = 0; ch < 32; ++ch) {
    int c0 = ch * 64;
    int buf = ch & 1;
    float z0 = io<ST>::ld(Z + (size_t)(bt0 + 0) * C_ + c0 + lane);
    float z1 = io<ST>::ld(Z + (size_t)(bt0 + 1) * C_ + c0 + lane);
    float z2 = io<ST>::ld(Z + (size_t)(bt0 + 2) * C_ + c0 + lane);
    float z3 = io<ST>::ld(Z + (size_t)(bt0 + 3) * C_ + c0 + lane);
    if (ch + 1 < 32) {
#pragma unroll
      for (int q = 0; q < 8; ++q) {
        int idx = q * 256 + tid;
        int cc = idx >> 5;
        int j4 = (idx & 31) * 4;
        *(float4*)&w1s[buf ^ 1][cc * 128 + j4] =
            *(const float4*)&W1[(size_t)(c0 + 64 + cc) * 160 + j4];
      }
    }
#pragma unroll
    for (int l = 0; l < 64; ++l) {
      float wa = w1s[buf][l * 128 + lane];
      float wb = w1s[buf][l * 128 + lane + 64];
      float s0 = bcast(z0, l), s1 = bcast(z1, l), s2 = bcast(z2, l), s3 = bcast(z3, l);
      acc[0][0] = fmaf(s0, wa, acc[0][0]); acc[0][1] = fmaf(s0, wb, acc[0][1]);
      acc[1][0] = fmaf(s1, wa, acc[1][0]); acc[1][1] = fmaf(s1, wb, acc[1][1]);
      acc[2][0] = fmaf(s2, wa, acc[2][0]); acc[2][1] = fmaf(s2, wb, acc[2][1]);
      acc[3][0] = fmaf(s3, wa, acc[3][0]); acc[3][1] = fmaf(s3, wb, acc[3][1]);
    }
    __syncthreads();
  }
#pragma unroll
  for (int tk = 0; tk < 4; ++tk) {
    P[(size_t)(bt0 + tk) * 128 + lane]      = tanhf(acc[tk][0]);
    P[(size_t)(bt0 + tk) * 128 + lane + 64] = tanhf(acc[tk][1]);
  }
}

// ---------------- K2 (fp32 legacy): four separate outputs ----------------
static __global__ __launch_bounds__(256) void k2_mix_f32(
    const float* __restrict__ hidden, const float* __restrict__ attn_x,
    const float* __restrict__ P, const float* __restrict__ W2,
    const float* __restrict__ maa_w, const float* __restrict__ maa_k,
    const float* __restrict__ maa_v, const float* __restrict__ maa_r,
    float* __restrict__ XW, float* __restrict__ XK,
    float* __restrict__ XV, float* __restrict__ XR) {
  int cb = blockIdx.x & 7;
  int tb = blockIdx.x >> 3;
  int c = cb * 256 + threadIdx.x;
  int bt0 = tb * 16;
  float xv_[16], xx_[16];
#pragma unroll
  for (int tk = 0; tk < 16; ++tk) {
    int bt = bt0 + tk;
    float x = hidden[(size_t)bt * C_ + c];
    int t = bt & (T_ - 1);
    int b = bt >> 12;
    float xp = (t == 0) ? attn_x[(size_t)b * C_ + c]
                        : hidden[(size_t)(bt - 1) * C_ + c];
    xv_[tk] = x;
    xx_[tk] = xp - x;
  }
#pragma unroll
  for (int f = 0; f < 4; ++f) {
    const float* mp = (f == 0) ? maa_w : (f == 1) ? maa_k : (f == 2) ? maa_v : maa_r;
    float* op       = (f == 0) ? XW    : (f == 1) ? XK    : (f == 2) ? XV    : XR;
    float w2r[32];
#pragma unroll
    for (int k = 0; k < 32; ++k) w2r[k] = W2[(size_t)(f * 32 + k) * C_ + c];
    float mf = mp[c];
    for (int tk = 0; tk < 16; ++tk) {
      const float4* p4 = (const float4*)(P + (size_t)(bt0 + tk) * 128 + f * 32);
      float a0 = 0.f, a1 = 0.f, a2 = 0.f, a3 = 0.f;
#pragma unroll
      for (int q = 0; q < 8; ++q) {
        float4 pv = p4[q];
        a0 = fmaf(pv.x, w2r[4 * q + 0], a0);
        a1 = fmaf(pv.y, w2r[4 * q + 1], a1);
        a2 = fmaf(pv.z, w2r[4 * q + 2], a2);
        a3 = fmaf(pv.w, w2r[4 * q + 3], a3);
      }
      float acc = (a0 + a1) + (a2 + a3);
      op[(size_t)(bt0 + tk) * C_ + c] = xv_[tk] + xx_[tk] * (mf + acc);
    }
  }
}

// ---------------- K2 (bf16 packed): XW, XV bf16; RKI = (k<<16)|r per elem ----------------
static __global__ __launch_bounds__(256) void k2_mix_bf16(
    const float* __restrict__ hidden, const float* __restrict__ attn_x,
    const float* __restrict__ P, const float* __restrict__ W2,
    const float* __restrict__ maa_w, const float* __restrict__ maa_k,
    const float* __restrict__ maa_v, const float* __restrict__ maa_r,
    u16* __restrict__ XW, u32* __restrict__ RKI, u16* __restrict__ XV) {
  int cb = blockIdx.x & 7;
  int tb = blockIdx.x >> 3;
  int c = cb * 256 + threadIdx.x;
  int bt0 = tb * 16;
  float xv_[16], xx_[16], xk_[16];
#pragma unroll
  for (int tk = 0; tk < 16; ++tk) {
    int bt = bt0 + tk;
    float x = hidden[(size_t)bt * C_ + c];
    int t = bt & (T_ - 1);
    int b = bt >> 12;
    float xp = (t == 0) ? attn_x[(size_t)b * C_ + c]
                        : hidden[(size_t)(bt - 1) * C_ + c];
    xv_[tk] = x;
    xx_[tk] = xp - x;
  }
#pragma unroll
  for (int f = 0; f < 4; ++f) {
    const float* mp = (f == 0) ? maa_w : (f == 1) ? maa_k : (f == 2) ? maa_v : maa_r;
    float w2r[32];
#pragma unroll
    for (int k = 0; k < 32; ++k) w2r[k] = W2[(size_t)(f * 32 + k) * C_ + c];
    float mf = mp[c];
    for (int tk = 0; tk < 16; ++tk) {
      const float4* p4 = (const float4*)(P + (size_t)(bt0 + tk) * 128 + f * 32);
      float a0 = 0.f, a1 = 0.f, a2 = 0.f, a3 = 0.f;
#pragma unroll
      for (int q = 0; q < 8; ++q) {
        float4 pv = p4[q];
        a0 = fmaf(pv.x, w2r[4 * q + 0], a0);
        a1 = fmaf(pv.y, w2r[4 * q + 1], a1);
        a2 = fmaf(pv.z, w2r[4 * q + 2], a2);
        a3 = fmaf(pv.w, w2r[4 * q + 3], a3);
      }
      float val = xv_[tk] + xx_[tk] * (mf + (a0 + a1) + (a2 + a3));
      size_t off = (size_t)(bt0 + tk) * C_ + c;
      if (f == 0)      io<u16>::st(XW + off, val);
      else if (f == 1) xk_[tk] = val;
      else if (f == 2) io<u16>::st(XV + off, val);
      else {  // f == 3: r -> low half, k -> high half
        u32 pk = (u32)io<u16>::cvt1(val) | ((u32)io<u16>::cvt1(xk_[tk]) << 16);
        RKI[off] = pk;
      }
    }
  }
}

// ---------------- K3 (bf16, MFMA): D1 = tanh(XW @ DW1) ----------------
static __global__ __launch_bounds__(256) void k3_mfma(
    const u16* __restrict__ XW, const u16* __restrict__ DW1T,
    float* __restrict__ D1) {
  int tid = threadIdx.x;
  int lane = tid & 63, wv = tid >> 6;
  int bt0 = blockIdx.x * 16;
  int j0 = wv * 16;
  int row = lane & 15, kg = lane >> 4;
  const u16* xa = XW   + (size_t)(bt0 + row) * C_ + kg * 8;
  const u16* bp = DW1T + (size_t)(j0 + row) * C_ + kg * 8;
  f32x4 acc = {0.f, 0.f, 0.f, 0.f};
#pragma unroll 8
  for (int c0 = 0; c0 < C_; c0 += 32) {
    bf16x8 a = *(const bf16x8*)(xa + c0);
    bf16x8 b = *(const bf16x8*)(bp + c0);
    acc = __builtin_amdgcn_mfma_f32_16x16x32_bf16(a, b, acc, 0, 0, 0);
  }
  int orow = bt0 + kg * 4;
#pragma unroll
  for (int rg = 0; rg < 4; ++rg)
    D1[(size_t)(orow + rg) * 64 + j0 + row] = tanhf(acc[rg]);
}

// ---------------- K3 (fp32 legacy) ----------------
template <typename ST>
static __global__ __launch_bounds__(256) void k3_d1(
    const ST* __restrict__ XW, const float* __restrict__ DW1,
    float* __restrict__ D1) {
  __shared__ float w1s[2][64 * 64];
  int tid = threadIdx.x;
  int lane = tid & 63;
  int wv = tid >> 6;
  int bt0 = blockIdx.x * 16 + wv * 4;
  float acc[4];
#pragma unroll
  for (int tk = 0; tk < 4; ++tk) acc[tk] = 0.f;

#pragma unroll
  for (int q = 0; q < 4; ++q) {
    int idx = q * 256 + tid;
    int cc = idx >> 4;
    int j4 = (idx & 15) * 4;
    *(float4*)&w1s[0][cc * 64 + j4] = *(const float4*)&DW1[(size_t)cc * 64 + j4];
  }
  __syncthreads();

#pragma unroll 1
  for (int ch = 0; ch < 32; ++ch) {
    int c0 = ch * 64;
    int buf = ch & 1;
    float z0 = io<ST>::ld(XW + (size_t)(bt0 + 0) * C_ + c0 + lane);
    float z1 = io<ST>::ld(XW + (size_t)(bt0 + 1) * C_ + c0 + lane);
    float z2 = io<ST>::ld(XW + (size_t)(bt0 + 2) * C_ + c0 + lane);
    float z3 = io<ST>::ld(XW + (size_t)(bt0 + 3) * C_ + c0 + lane);
    if (ch + 1 < 32) {
#pragma unroll
      for (int q = 0; q < 4; ++q) {
        int idx = q * 256 + tid;
        int cc = idx >> 4;
        int j4 = (idx & 15) * 4;
        *(float4*)&w1s[buf ^ 1][cc * 64 + j4] =
            *(const float4*)&DW1[(size_t)(c0 + 64 + cc) * 64 + j4];
      }
    }
#pragma unroll
    for (int l = 0; l < 64; ++l) {
      float wa = w1s[buf][l * 64 + lane];
      acc[0] = fmaf(bcast(z0, l), wa, acc[0]);
      acc[1] = fmaf(bcast(z1, l), wa, acc[1]);
      acc[2] = fmaf(bcast(z2, l), wa, acc[2]);
      acc[3] = fmaf(bcast(z3, l), wa, acc[3]);
    }
    __syncthreads();
  }
#pragma unroll
  for (int tk = 0; tk < 4; ++tk)
    D1[(size_t)(bt0 + tk) * 64 + lane] = tanhf(acc[tk]);
}

// ---------------- K4: DEC = exp(-exp(time_decay + D1 @ DW2)) ----------------
template <typename ST>
static __global__ __launch_bounds__(256) void k4_decay(
    const float* __restrict__ D1, const float* __restrict__ DW2,
    const float* __restrict__ td, ST* __restrict__ DEC) {
  int cb = blockIdx.x & 7;
  int tb = blockIdx.x >> 3;
  int c = cb * 256 + threadIdx.x;
  int bt0 = tb * 16;
  float w2r[64];
#pragma unroll
  for (int k = 0; k < 64; ++k) w2r[k] = DW2[(size_t)k * C_ + c];
  float tdv = td[c];
  for (int tk = 0; tk < 16; ++tk) {
    const float4* d4 = (const float4*)(D1 + (size_t)(bt0 + tk) * 64);
    float a0 = 0.f, a1 = 0.f, a2 = 0.f, a3 = 0.f;
#pragma unroll
    for (int q = 0; q < 16; ++q) {
      float4 dv = d4[q];
      a0 = fmaf(dv.x, w2r[4 * q + 0], a0);
      a1 = fmaf(dv.y, w2r[4 * q + 1], a1);
      a2 = fmaf(dv.z, w2r[4 * q + 2], a2);
      a3 = fmaf(dv.w, w2r[4 * q + 3], a3);
    }
    float w = tdv + (a0 + a1) + (a2 + a3);
    io<ST>::st(DEC + (size_t)(bt0 + tk) * C_ + c, expf(-expf(w)));
  }
}

// ---------------- K5 (fp32 legacy): round-0 register-broadcast version ----------------
static __global__ __launch_bounds__(256) void k5_intra_f32(
    float* XRQ,
    const float* __restrict__ XK, const float* __restrict__ XV,
    const float* __restrict__ DEC, const float* __restrict__ faaaa,
    float* __restrict__ UC, float* __restrict__ DCp, float* __restrict__ Y) {
  int m = threadIdx.x & 63;
  int chunk = blockIdx.x * 4 + (threadIdx.x >> 6);
  int cc = chunk & (NC_ - 1);
  int h = (chunk >> 6) & (H_ - 1);
  int b = chunk >> 11;
  float u = faaaa[h];
  float s[64];
#pragma unroll
  for (int n = 0; n < 64; ++n) s[n] = 0.f;
  float areg = 1.f;
  size_t row = ((size_t)(b * T_ + cc * L_)) * C_ + h * N_;
  for (int t = 0; t < L_; ++t, row += C_) {
    float vm = XV[row + m];
    float wl = DEC[row + m];
    float kl = XK[row + m];
    float rl = XRQ[row + m];
    float dot = rl * kl;
#pragma unroll
    for (int mk = 32; mk >= 1; mk >>= 1) dot += __shfl_xor(dot, mk, 64);
    float y0 = u * vm * dot, y1 = 0.f, y2 = 0.f, y3 = 0.f;
#pragma unroll
    for (int n = 0; n < 64; n += 4) {
      float rn, kn, wn;
      rn = bcast(rl, n + 0); kn = bcast(kl, n + 0); wn = bcast(wl, n + 0);
      y0 = fmaf(rn, s[n + 0], y0); s[n + 0] = fmaf(wn, s[n + 0], kn * vm);
      rn = bcast(rl, n + 1); kn = bcast(kl, n + 1); wn = bcast(wl, n + 1);
      y1 = fmaf(rn, s[n + 1], y1); s[n + 1] = fmaf(wn, s[n + 1], kn * vm);
      rn = bcast(rl, n + 2); kn = bcast(kl, n + 2); wn = bcast(wl, n + 2);
      y2 = fmaf(rn, s[n + 2], y2); s[n + 2] = fmaf(wn, s[n + 2], kn * vm);
      rn = bcast(rl, n + 3); kn = bcast(kl, n + 3); wn = bcast(wl, n + 3);
      y3 = fmaf(rn, s[n + 3], y3); s[n + 3] = fmaf(wn, s[n + 3], kn * vm);
    }
    XRQ[row + m] = rl * areg;
    areg *= wl;
    Y[row + m] = (y0 + y1) + (y2 + y3);
  }
  size_t ucb = (size_t)chunk * (N_ * N_);
#pragma unroll
  for (int n = 0; n < 64; ++n) UC[ucb + (size_t)n * 64 + m] = s[n];
  DCp[(size_t)chunk * N_ + m] = areg;
}

// ---------------- K5 (bf16 v2): 2 waves per chunk, n-split ----------------
// Each wave owns 32 of the 64 state rows; per-wave inner loop halves (16 broadcast
// groups). y-partials combine via double-buffered LDS + one __syncthreads per t.
// Barrier(t-1) also orders wave1's v-prefetch of row t before wave0's RQ store of
// row t (read-before-write guaranteed; the clamped last-iteration prefetch is racy
// but its value is discarded). Readlane bases are template constants.
template <int BASE>
static __device__ __forceinline__ void k5_inner(
    u32 rki, u32 wpk, float vm, float* s,
    float& y0, float& y1, float& y2, float& y3) {
#pragma unroll
  for (int i = 0; i < 16; ++i) {
    u32 rk0 = bcast_u(rki, 2 * (BASE + i));
    u32 rk1 = bcast_u(rki, 2 * (BASE + i) + 1);
    u32 wp  = bcast_u(wpk, BASE + i);
    float r0 = bflo(rk0), k0 = bfhi(rk0);
    float r1 = bflo(rk1), k1 = bfhi(rk1);
    float w0 = bflo(wp),  w1 = bfhi(wp);
    int n = 2 * i;
    if (i & 1) {
      y2 = fmaf(r0, s[n], y2);     s[n]     = fmaf(w0, s[n],     k0 * vm);
      y3 = fmaf(r1, s[n + 1], y3); s[n + 1] = fmaf(w1, s[n + 1], k1 * vm);
    } else {
      y0 = fmaf(r0, s[n], y0);     s[n]     = fmaf(w0, s[n],     k0 * vm);
      y1 = fmaf(r1, s[n + 1], y1); s[n + 1] = fmaf(w1, s[n + 1], k1 * vm);
    }
  }
}

static __global__ __launch_bounds__(256) void k5_intra_bf16_v2(
    const u32* __restrict__ RKI, u16* XVRQ,
    const u16* __restrict__ DEC, const float* __restrict__ faaaa,
    u16* __restrict__ UC, float* __restrict__ DCp, float* __restrict__ Y) {
  __shared__ float ycomb[2][2][64];
  int m = threadIdx.x & 63;
  int wv = threadIdx.x >> 6;
  int cw = wv >> 1;                 // chunk within block (0,1)
  int half = wv & 1;                // n-half (0: n<32, 1: n>=32)
  int chunk = blockIdx.x * 2 + cw;
  int cc = chunk & (NC_ - 1);
  int h = (chunk >> 6) & (H_ - 1);
  int b = chunk >> 11;
  float u = faaaa[h];
  float s[32];
#pragma unroll
  for (int n = 0; n < 32; ++n) s[n] = 0.f;
  float areg = 1.f;
  size_t row = ((size_t)(b * T_ + cc * L_)) * C_ + h * N_;
  u32 nrki = RKI[row + m];
  float nvm = io<u16>::ld(XVRQ + row + m);
  float nwl = io<u16>::ld(DEC + row + m);
  u32 nwpk = ((const u32*)(DEC + row))[m & 31];
#pragma unroll 1
  for (int t = 0; t < L_; ++t, row += C_) {
    u32 rki = nrki;
    float vm = nvm;
    float wl = nwl;
    u32 wpk = nwpk;
    size_t nx = (t + 1 < L_) ? row + C_ : row;   // clamped prefetch (last iter: dummy)
    nrki = RKI[nx + m];
    nvm = io<u16>::ld(XVRQ + nx + m);
    nwl = io<u16>::ld(DEC + nx + m);
    nwpk = ((const u32*)(DEC + nx))[m & 31];
    float rl = bflo(rki), kl = bfhi(rki);
    float dot = rl * kl;
#pragma unroll
    for (int mk = 32; mk >= 1; mk >>= 1) dot += __shfl_xor(dot, mk, 64);
    float y0 = 0.f, y1 = 0.f, y2 = 0.f, y3 = 0.f;
    if (half) {
      k5_inner<16>(rki, wpk, vm, s, y0, y1, y2, y3);
    } else {
      y0 = u * vm * dot;
      k5_inner<0>(rki, wpk, vm, s, y0, y1, y2, y3);
    }
    float yp = (y0 + y1) + (y2 + y3);
    if (half) {
      ycomb[cw][t & 1][m] = yp;
    } else {
      io<u16>::st(XVRQ + row + m, rl * areg);    // RQ = r * cumdecay (pre-step)
    }
    areg *= wl;
    __syncthreads();
    if (!half) Y[row + m] = yp + ycomb[cw][t & 1][m];
  }
  size_t ucb = (size_t)chunk * (N_ * N_) + (size_t)half * 32 * 64;
#pragma unroll
  for (int n = 0; n < 32; ++n) io<u16>::st(UC + ucb + (size_t)n * 64 + m, s[n]);
  if (!half) DCp[(size_t)chunk * N_ + m] = areg;
}

// ---------------- K6 (fp32 legacy): inter-chunk state scan ----------------
template <typename ST>
static __global__ __launch_bounds__(256) void k6_scan(
    const float* __restrict__ attn_kv, ST* __restrict__ UC,
    const float* __restrict__ DCp) {
  int msel = blockIdx.x & 3;
  int bh = blockIdx.x >> 2;
  int ml = threadIdx.x & 15;
  int n0 = threadIdx.x >> 4;
  int m = msel * 16 + ml;
  float s[4];
#pragma unroll
  for (int i = 0; i < 4; ++i) {
    int n = n0 + 16 * i;
    s[i] = attn_kv[((size_t)bh * N_ + n) * N_ + m];
  }
  for (int c = 0; c < NC_; ++c) {
    size_t cb = (size_t)bh * NC_ + c;
#pragma unroll
    for (int i = 0; i < 4; ++i) {
      int n = n0 + 16 * i;
      size_t idx = (cb * (size_t)(N_ * N_)) + (size_t)n * 64 + m;
      float uc = io<ST>::ld(UC + idx);
      float dc = DCp[cb * N_ + n];
      io<ST>::st(UC + idx, s[i]);
      s[i] = fmaf(dc, s[i], uc);
    }
  }
}

// ---------------- K6 (bf16, paired): dword scans with prefetch ----------------
static __global__ __launch_bounds__(256) void k6_scan_v2(
    const float* __restrict__ attn_kv, u16* __restrict__ UC,
    const float* __restrict__ DCp) {
  int bh = blockIdx.x >> 3;
  int sub = blockIdx.x & 7;
  int tid = threadIdx.x;
  int n = sub * 8 + (tid >> 5);
  int mp = tid & 31;                       // m = 2*mp, 2*mp+1
  float2 s = *(const float2*)(attn_kv + ((size_t)bh * N_ + n) * N_ + 2 * mp);
  u32* UCd = (u32*)UC;
  size_t base = ((size_t)bh * NC_) * 2048 + (size_t)n * 32 + mp;
  u32 nuc = UCd[base];
  float ndc = DCp[((size_t)bh * NC_) * N_ + n];
#pragma unroll 1
  for (int c = 0; c < NC_; ++c) {
    u32 uc = nuc;
    float dc = ndc;
    size_t idx = base + (size_t)c * 2048;
    if (c + 1 < NC_) {
      nuc = UCd[idx + 2048];
      ndc = DCp[((size_t)bh * NC_ + c + 1) * N_ + n];
    }
    u32 pk = (u32)io<u16>::cvt1(s.x) | ((u32)io<u16>::cvt1(s.y) << 16);
    UCd[idx] = pk;                          // state at chunk start (for k7)
    s.x = fmaf(dc, s.x, bflo(uc));
    s.y = fmaf(dc, s.y, bfhi(uc));
  }
}

// ---------------- K7 (fp32 legacy) ----------------
static __global__ __launch_bounds__(256) void k7_state_f32(
    const float* __restrict__ RQ, const float* __restrict__ UC,
    float* __restrict__ Y) {
  int m = threadIdx.x & 63;
  int chunk = blockIdx.x * 4 + (threadIdx.x >> 6);
  int cc = chunk & (NC_ - 1);
  int h = (chunk >> 6) & (H_ - 1);
  int b = chunk >> 11;
  float sc[64];
  size_t ucb = (size_t)chunk * (N_ * N_);
#pragma unroll
  for (int n = 0; n < 64; ++n) sc[n] = UC[ucb + (size_t)n * 64 + m];
  size_t row = ((size_t)(b * T_ + cc * L_)) * C_ + h * N_;
  for (int t = 0; t < L_; ++t, row += C_) {
    float ql = RQ[row + m];
    float y0 = Y[row + m], y1 = 0.f, y2 = 0.f, y3 = 0.f;
#pragma unroll
    for (int n = 0; n < 64; n += 4) {
      y0 = fmaf(bcast(ql, n + 0), sc[n + 0], y0);
      y1 = fmaf(bcast(ql, n + 1), sc[n + 1], y1);
      y2 = fmaf(bcast(ql, n + 2), sc[n + 2], y2);
      y3 = fmaf(bcast(ql, n + 3), sc[n + 3], y3);
    }
    Y[row + m] = (y0 + y1) + (y2 + y3);
  }
}

// ---------------- K7 (bf16, MFMA): Y += RQ(64x64) @ S0(64x64) per chunk ----------------
static __global__ __launch_bounds__(256) void k7_mfma(
    const u16* __restrict__ RQ, const u16* __restrict__ UC,
    float* __restrict__ Y) {
  __shared__ u16 st[64][64];   // st[m][n ^ ((m&7)<<3)] = S0[n][m]
  int tid = threadIdx.x;
  int chunk = blockIdx.x;
  int cc = chunk & (NC_ - 1);
  int h = (chunk >> 6) & (H_ - 1);
  int b = chunk >> 11;
  const u16* S0 = UC + (size_t)chunk * (N_ * N_);
  {
    int n = tid >> 2;
    int m0 = (tid & 3) << 4;
#pragma unroll
    for (int j = 0; j < 16; ++j) {
      int m = m0 + j;
      st[m][n ^ ((m & 7) << 3)] = S0[n * 64 + m];
    }
  }
  __syncthreads();
  int lane = tid & 63;
  int wv = tid >> 6;
  int trow = lane & 15;
  int kg = lane >> 4;
  int t0 = wv << 4;
  size_t arow = ((size_t)(b * T_ + cc * L_ + t0 + trow)) * C_ + h * N_;
  bf16x8 a0 = *(const bf16x8*)(RQ + arow + kg * 8);
  bf16x8 a1 = *(const bf16x8*)(RQ + arow + 32 + kg * 8);
#pragma unroll
  for (int ct = 0; ct < 4; ++ct) {
    int col = ct * 16 + trow;
    int sw = (col & 7) << 3;
    bf16x8 b0 = *(const bf16x8*)&st[col][(kg * 8) ^ sw];
    bf16x8 b1 = *(const bf16x8*)&st[col][(32 + kg * 8) ^ sw];
    f32x4 c = {0.f, 0.f, 0.f, 0.f};
    c = __builtin_amdgcn_mfma_f32_16x16x32_bf16(a0, b0, c, 0, 0, 0);
    c = __builtin_amdgcn_mfma_f32_16x16x32_bf16(a1, b1, c, 0, 0, 0);
    size_t ybase = ((size_t)(b * T_ + cc * L_ + t0 + kg * 4)) * C_ + h * N_ + ct * 16 + trow;
#pragma unroll
    for (int rg = 0; rg < 4; ++rg)
      Y[ybase + (size_t)rg * C_] += c[rg];
  }
}

// ---------------- host ----------------
static void run_f32(void* const* d_in, void* d_out, void* d_ws, hipStream_t stream) {
  const float* hidden = (const float*)d_in[0];
  const float* attn_x = (const float*)d_in[1];
  const float* attn_kv = (const float*)d_in[2];
  const float* maa_x = (const float*)d_in[4];
  const float* maa_w = (const float*)d_in[5];
  const float* maa_k = (const float*)d_in[6];
  const float* maa_v = (const float*)d_in[7];
  const float* maa_r = (const float*)d_in[8];
  const float* W1 = (const float*)d_in[10];
  const float* W2 = (const float*)d_in[11];
  const float* tdec = (const float*)d_in[12];
  const float* DW1 = (const float*)d_in[13];
  const float* DW2 = (const float*)d_in[14];
  const float* faaaa = (const float*)d_in[15];

  const size_t BIG = (size_t)BT_ * C_;
  char* p = (char*)d_ws;
  float* A   = (float*)p; p += BIG * 4;
  float* XK  = (float*)p; p += BIG * 4;
  float* XV  = (float*)p; p += BIG * 4;
  float* XRQ = (float*)p; p += BIG * 4;
  float* UC  = (float*)p; p += BIG * 4;
  float* P   = (float*)p; p += (size_t)BT_ * 128 * 4;
  float* D1  = (float*)p; p += (size_t)BT_ * 64 * 4;
  float* DCp = (float*)p;
  float* Y = (float*)d_out;

  k0_z<float>    <<<16384, 256, 0, stream>>>(hidden, attn_x, maa_x, A);
  k1_p<float>    <<<BT_ / 16, 256, 0, stream>>>(A, W1, P);
  k2_mix_f32     <<<(BT_ / 16) * 8, 256, 0, stream>>>(hidden, attn_x, P, W2,
                                                      maa_w, maa_k, maa_v, maa_r,
                                                      A, XK, XV, XRQ);
  k3_d1<float>   <<<BT_ / 16, 256, 0, stream>>>(A, DW1, D1);
  k4_decay<float><<<(BT_ / 16) * 8, 256, 0, stream>>>(D1, DW2, tdec, A);
  k5_intra_f32   <<<B_ * H_ * NC_ / 4, 256, 0, stream>>>(XRQ, XK, XV, A, faaaa,
                                                         UC, DCp, Y);
  k6_scan<float> <<<B_ * H_ * 4, 256, 0, stream>>>(attn_kv, UC, DCp);
  k7_state_f32   <<<B_ * H_ * NC_ / 4, 256, 0, stream>>>(XRQ, UC, Y);
}

static void run_bf16(void* const* d_in, void* d_out, void* d_ws, hipStream_t stream) {
  const float* hidden = (const float*)d_in[0];
  const float* attn_x = (const float*)d_in[1];
  const float* attn_kv = (const float*)d_in[2];
  const float* maa_x = (const float*)d_in[4];
  const float* maa_w = (const float*)d_in[5];
  const float* maa_k = (const float*)d_in[6];
  const float* maa_v = (const float*)d_in[7];
  const float* maa_r = (const float*)d_in[8];
  const float* W1 = (const float*)d_in[10];
  const float* W2 = (const float*)d_in[11];
  const float* tdec = (const float*)d_in[12];
  const float* DW1 = (const float*)d_in[13];
  const float* DW2 = (const float*)d_in[14];
  const float* faaaa = (const float*)d_in[15];

  const size_t BIG = (size_t)BT_ * C_;
  char* p = (char*)d_ws;
  u16* A    = (u16*)p; p += BIG * 2;         // Z -> XW -> DEC
  u32* RKI  = (u32*)p; p += BIG * 4;         // (k<<16)|r packed
  u16* XVRQ = (u16*)p; p += BIG * 2;         // XV, overwritten by RQ in k5
  u16* UC   = (u16*)p; p += BIG * 2;
  float* P   = (float*)p; p += (size_t)BT_ * 128 * 4;
  float* D1  = (float*)p; p += (size_t)BT_ * 64 * 4;
  float* DCp = (float*)p;
  float* Y = (float*)d_out;
  // Scratch aliasing: W1T (512 KB) lives in the D1 region (D1 written later by k3);
  // DW1T (256 KB) lives in the DCp region (DCp written later by k5). Zero extra ws.
  u16* W1T  = (u16*)D1;
  u16* DW1T = (u16*)DCp;

  wt_prep      <<<96, 256, 0, stream>>>(W1, DW1, W1T, DW1T);
  k0_z<u16>    <<<16384, 256, 0, stream>>>(hidden, attn_x, maa_x, A);
  k1_mfma      <<<BT_ / 16, 256, 0, stream>>>(A /*Z*/, W1T, P);
  k2_mix_bf16  <<<(BT_ / 16) * 8, 256, 0, stream>>>(hidden, attn_x, P, W2,
                                                    maa_w, maa_k, maa_v, maa_r,
                                                    A, RKI, XVRQ);
  k3_mfma      <<<BT_ / 16, 256, 0, stream>>>(A /*XW*/, DW1T, D1);
  k4_decay<u16><<<(BT_ / 16) * 8, 256, 0, stream>>>(D1, DW2, tdec, A);
  k5_intra_bf16_v2<<<B_ * H_ * NC_ / 2, 256, 0, stream>>>(RKI, XVRQ, A, faaaa,
                                                          UC, DCp, Y);
  k6_scan_v2   <<<B_ * H_ * 8, 256, 0, stream>>>(attn_kv, UC, DCp);
  k7_mfma      <<<B_ * H_ * NC_, 256, 0, stream>>>(XVRQ, UC, Y);
}

extern "C" void kernel_launch(void* const* d_in, const int* in_sizes, int n_in,
                              void* d_out, int out_size, void* d_ws, size_t ws_size,
                              hipStream_t stream) {
  const size_t BIG = (size_t)BT_ * C_;
  const size_t small = (size_t)BT_ * 128 * 4 + (size_t)BT_ * 64 * 4 +
                       (size_t)B_ * H_ * NC_ * N_ * 4;
  const size_t need_f32 = BIG * 4 * 5 + small;   // ~343 MB
  if (ws_size >= need_f32)
    run_f32(d_in, d_out, d_ws, stream);
  else
    run_bf16(d_in, d_out, d_ws, stream);         // bf16 storage + packed RKI, ~175 MB
}

// Round 9
// 587.557 us; speedup vs baseline: 1.2759x; 1.2759x over previous
//
#include <hip/hip_runtime.h>
#include <cmath>

#define B_ 2
#define T_ 4096
#define C_ 2048
#define H_ 32
#define N_ 64
#define L_ 64
#define NC_ 64
#define BT_ 8192

typedef unsigned short u16;
typedef unsigned int u32;
typedef __attribute__((ext_vector_type(8))) short bf16x8;
typedef __attribute__((ext_vector_type(4))) float f32x4;

// ---------- storage abstraction: fp32 or bf16-in-memory (compute fp32) ----------
template <typename T> struct io;
template <> struct io<float> {
  static __device__ __forceinline__ float  ld (const float* p) { return *p; }
  static __device__ __forceinline__ float4 ld4(const float* p) { return *(const float4*)p; }
  static __device__ __forceinline__ void st (float* p, float v) { *p = v; }
  static __device__ __forceinline__ void st4(float* p, float4 v) { *(float4*)p = v; }
};
template <> struct io<u16> {
  static __device__ __forceinline__ float ld(const u16* p) {
    return __uint_as_float((unsigned)(*p) << 16);
  }
  static __device__ __forceinline__ float4 ld4(const u16* p) {
    ushort4 u = *(const ushort4*)p;
    return make_float4(__uint_as_float((unsigned)u.x << 16),
                       __uint_as_float((unsigned)u.y << 16),
                       __uint_as_float((unsigned)u.z << 16),
                       __uint_as_float((unsigned)u.w << 16));
  }
  static __device__ __forceinline__ u16 cvt1(float x) {
    unsigned u = __float_as_uint(x);
    return (u16)((u + 0x7fffu + ((u >> 16) & 1u)) >> 16);
  }
  static __device__ __forceinline__ void st(u16* p, float v) { *p = cvt1(v); }
  static __device__ __forceinline__ void st4(u16* p, float4 v) {
    ushort4 u;
    u.x = cvt1(v.x); u.y = cvt1(v.y); u.z = cvt1(v.z); u.w = cvt1(v.w);
    *(ushort4*)p = u;
  }
};

// broadcast lane `lane`'s value of v to all lanes (v_readlane)
static __device__ __forceinline__ float bcast(float v, int lane) {
  return __uint_as_float(__builtin_amdgcn_readlane(__float_as_uint(v), lane));
}
static __device__ __forceinline__ u32 bcast_u(u32 v, int lane) {
  return (u32)__builtin_amdgcn_readlane((int)v, lane);
}
// bf16-pair unpack; on a uniform (readlane) value these lower to s_lshl/s_and (SALU)
static __device__ __forceinline__ float bflo(u32 u) { return __uint_as_float(u << 16); }
static __device__ __forceinline__ float bfhi(u32 u) { return __uint_as_float(u & 0xffff0000u); }

// ---------------- K0: Z = x + (shift(x) - x) * maa_x ----------------
template <typename ST>
static __global__ __launch_bounds__(256) void k0_z(
    const float* __restrict__ hidden, const float* __restrict__ attn_x,
    const float* __restrict__ maa_x, ST* __restrict__ Z) {
  int idx = blockIdx.x * 256 + threadIdx.x;
  int base = idx * 4;
  int bt = base >> 11;           // / C_
  int c  = base & (C_ - 1);
  int t  = bt & (T_ - 1);
  int b  = bt >> 12;
  float4 x = *(const float4*)(hidden + (size_t)base);
  float4 xp;
  if (t == 0) xp = *(const float4*)(attn_x + (size_t)b * C_ + c);
  else        xp = *(const float4*)(hidden + (size_t)base - C_);
  float4 mx = *(const float4*)(maa_x + c);
  float4 z;
  z.x = x.x + (xp.x - x.x) * mx.x;
  z.y = x.y + (xp.y - x.y) * mx.y;
  z.z = x.z + (xp.z - x.z) * mx.z;
  z.w = x.w + (xp.w - x.w) * mx.w;
  io<ST>::st4(Z + (size_t)base, z);
}

// ---------------- WT: transpose+convert weights to bf16 ----------------
// Generic 64x64 tile transpose a-major src -> b-major bf16 dst.
// blocks 0..63   : W1  [2048c][160row j128] -> W1T  [128j][2048c]
// blocks 64..95  : DW1 [2048c][64j]         -> DW1T [64j][2048c]
// blocks 96..159 : W2  [128j][2048c]        -> W2T  [2048c][128j]
// blocks 160..191: DW2 [64j][2048c]         -> DW2T [2048c][64j]
static __global__ __launch_bounds__(256) void wt_prep(
    const float* __restrict__ W1, const float* __restrict__ DW1,
    const float* __restrict__ W2, const float* __restrict__ DW2,
    u16* __restrict__ W1T, u16* __restrict__ DW1T,
    u16* __restrict__ W2T, u16* __restrict__ DW2T) {
  __shared__ u16 tile[64][65];
  int blk = blockIdx.x;
  const float* src; u16* dst; int a0, b0, srcld, dstld;
  if (blk < 64)       { src = W1;  dst = W1T;  a0 = (blk >> 1) * 64;        b0 = (blk & 1) * 64;        srcld = 160;  dstld = 2048; }
  else if (blk < 96)  { src = DW1; dst = DW1T; a0 = (blk - 64) * 64;        b0 = 0;                     srcld = 64;   dstld = 2048; }
  else if (blk < 160) { src = W2;  dst = W2T;  a0 = ((blk - 96) & 1) * 64;  b0 = ((blk - 96) >> 1) * 64; srcld = 2048; dstld = 128; }
  else                { src = DW2; dst = DW2T; a0 = 0;                      b0 = (blk - 160) * 64;       srcld = 2048; dstld = 64; }
  int tid = threadIdx.x;
  int bb = tid & 63, ar = tid >> 6;
#pragma unroll
  for (int i = 0; i < 16; ++i) {
    int a = ar + i * 4;
    tile[a][bb] = io<u16>::cvt1(src[(size_t)(a0 + a) * srcld + b0 + bb]);
  }
  __syncthreads();
  int aw = tid & 63, br = tid >> 6;
#pragma unroll
  for (int i = 0; i < 16; ++i) {
    int b = br + i * 4;
    dst[(size_t)(b0 + b) * dstld + a0 + aw] = tile[aw][b];
  }
}

// ---------------- K1 (bf16, MFMA): P = tanh(Z @ W1), P stored bf16 ----------------
static __global__ __launch_bounds__(256) void k1_mfma(
    const u16* __restrict__ Z, const u16* __restrict__ W1T,
    u16* __restrict__ Pb) {
  int tid = threadIdx.x;
  int lane = tid & 63, wv = tid >> 6;
  int bt0 = blockIdx.x * 16;
  int j0 = wv * 32;
  int row = lane & 15, kg = lane >> 4;
  const u16* za  = Z   + (size_t)(bt0 + row) * C_ + kg * 8;
  const u16* b0p = W1T + (size_t)(j0 + row) * C_ + kg * 8;
  const u16* b1p = W1T + (size_t)(j0 + 16 + row) * C_ + kg * 8;
  f32x4 acc0 = {0.f, 0.f, 0.f, 0.f}, acc1 = {0.f, 0.f, 0.f, 0.f};
#pragma unroll 8
  for (int c0 = 0; c0 < C_; c0 += 32) {
    bf16x8 a  = *(const bf16x8*)(za + c0);
    bf16x8 b0 = *(const bf16x8*)(b0p + c0);
    bf16x8 b1 = *(const bf16x8*)(b1p + c0);
    acc0 = __builtin_amdgcn_mfma_f32_16x16x32_bf16(a, b0, acc0, 0, 0, 0);
    acc1 = __builtin_amdgcn_mfma_f32_16x16x32_bf16(a, b1, acc1, 0, 0, 0);
  }
  int orow = bt0 + kg * 4;
#pragma unroll
  for (int rg = 0; rg < 4; ++rg) {
    Pb[(size_t)(orow + rg) * 128 + j0 + row]      = io<u16>::cvt1(tanhf(acc0[rg]));
    Pb[(size_t)(orow + rg) * 128 + j0 + 16 + row] = io<u16>::cvt1(tanhf(acc1[rg]));
  }
}

// ---------------- K1 (fp32 legacy): readlane-broadcast GEMM ----------------
template <typename ST>
static __global__ __launch_bounds__(256) void k1_p(
    const ST* __restrict__ Z, const float* __restrict__ W1,
    float* __restrict__ P) {
  __shared__ float w1s[2][64 * 128];
  int tid = threadIdx.x;
  int lane = tid & 63;
  int wv = tid >> 6;
  int bt0 = blockIdx.x * 16 + wv * 4;
  float acc[4][2];
#pragma unroll
  for (int tk = 0; tk < 4; ++tk) { acc[tk][0] = 0.f; acc[tk][1] = 0.f; }

#pragma unroll
  for (int q = 0; q < 8; ++q) {
    int idx = q * 256 + tid;
    int cc = idx >> 5;
    int j4 = (idx & 31) * 4;
    *(float4*)&w1s[0][cc * 128 + j4] = *(const float4*)&W1[(size_t)cc * 160 + j4];
  }
  __syncthreads();

#pragma unroll 1
  for (int ch = 0; ch < 32; ++ch) {
    int c0 = ch * 64;
    int buf = ch & 1;
    float z0 = io<ST>::ld(Z + (size_t)(bt0 + 0) * C_ + c0 + lane);
    float z1 = io<ST>::ld(Z + (size_t)(bt0 + 1) * C_ + c0 + lane);
    float z2 = io<ST>::ld(Z + (size_t)(bt0 + 2) * C_ + c0 + lane);
    float z3 = io<ST>::ld(Z + (size_t)(bt0 + 3) * C_ + c0 + lane);
    if (ch + 1 < 32) {
#pragma unroll
      for (int q = 0; q < 8; ++q) {
        int idx = q * 256 + tid;
        int cc = idx >> 5;
        int j4 = (idx & 31) * 4;
        *(float4*)&w1s[buf ^ 1][cc * 128 + j4] =
            *(const float4*)&W1[(size_t)(c0 + 64 + cc) * 160 + j4];
      }
    }
#pragma unroll
    for (int l = 0; l < 64; ++l) {
      float wa = w1s[buf][l * 128 + lane];
      float wb = w1s[buf][l * 128 + lane + 64];
      float s0 = bcast(z0, l), s1 = bcast(z1, l), s2 = bcast(z2, l), s3 = bcast(z3, l);
      acc[0][0] = fmaf(s0, wa, acc[0][0]); acc[0][1] = fmaf(s0, wb, acc[0][1]);
      acc[1][0] = fmaf(s1, wa, acc[1][0]); acc[1][1] = fmaf(s1, wb, acc[1][1]);
      acc[2][0] = fmaf(s2, wa, acc[2][0]); acc[2][1] = fmaf(s2, wb, acc[2][1]);
      acc[3][0] = fmaf(s3, wa, acc[3][0]); acc[3][1] = fmaf(s3, wb, acc[3][1]);
    }
    __syncthreads();
  }
#pragma unroll
  for (int tk = 0; tk < 4; ++tk) {
    P[(size_t)(bt0 + tk) * 128 + lane]      = tanhf(acc[tk][0]);
    P[(size_t)(bt0 + tk) * 128 + lane + 64] = tanhf(acc[tk][1]);
  }
}

// ---------------- K2 (bf16, MFMA): x-mix via matrix cores ----------------
// m_f = P @ W2_f (K=32, one MFMA per f); epilogue computes
// val_f = x + xx*(maa_f + m_f) and writes XW, XV, RKI=(k<<16)|r.
static __global__ __launch_bounds__(256) void k2_mfma(
    const float* __restrict__ hidden, const float* __restrict__ attn_x,
    const u16* __restrict__ Pb, const u16* __restrict__ W2T,
    const float* __restrict__ maa_w, const float* __restrict__ maa_k,
    const float* __restrict__ maa_v, const float* __restrict__ maa_r,
    u16* __restrict__ XW, u32* __restrict__ RKI, u16* __restrict__ XV) {
  int tid = threadIdx.x;
  int lane = tid & 63, wv = tid >> 6;
  int bt0 = blockIdx.x * 16;
  int row = lane & 15, kg = lane >> 4;
  const u16* pa = Pb + (size_t)(bt0 + row) * 128 + kg * 8;
  bf16x8 a0 = *(const bf16x8*)(pa);        // f=0 (w), j 0..31
  bf16x8 a1 = *(const bf16x8*)(pa + 32);   // f=1 (k)
  bf16x8 a2 = *(const bf16x8*)(pa + 64);   // f=2 (v)
  bf16x8 a3 = *(const bf16x8*)(pa + 96);   // f=3 (r)
#pragma unroll 1
  for (int it = 0; it < 32; ++it) {
    int c = it * 64 + wv * 16 + row;
    const u16* wb = W2T + (size_t)c * 128 + kg * 8;
    bf16x8 b0 = *(const bf16x8*)(wb);
    bf16x8 b1 = *(const bf16x8*)(wb + 32);
    bf16x8 b2 = *(const bf16x8*)(wb + 64);
    bf16x8 b3 = *(const bf16x8*)(wb + 96);
    f32x4 z = {0.f, 0.f, 0.f, 0.f};
    f32x4 m0 = __builtin_amdgcn_mfma_f32_16x16x32_bf16(a0, b0, z, 0, 0, 0);
    f32x4 m1 = __builtin_amdgcn_mfma_f32_16x16x32_bf16(a1, b1, z, 0, 0, 0);
    f32x4 m2 = __builtin_amdgcn_mfma_f32_16x16x32_bf16(a2, b2, z, 0, 0, 0);
    f32x4 m3 = __builtin_amdgcn_mfma_f32_16x16x32_bf16(a3, b3, z, 0, 0, 0);
    float mwc = maa_w[c], mkc = maa_k[c], mvc = maa_v[c], mrc = maa_r[c];
#pragma unroll
    for (int rg = 0; rg < 4; ++rg) {
      int bt = bt0 + kg * 4 + rg;
      float x = hidden[(size_t)bt * C_ + c];
      float xp = ((bt & (T_ - 1)) == 0) ? attn_x[(size_t)(bt >> 12) * C_ + c]
                                        : hidden[(size_t)(bt - 1) * C_ + c];
      float xx = xp - x;
      float vw = x + xx * (mwc + m0[rg]);
      float vk = x + xx * (mkc + m1[rg]);
      float vv = x + xx * (mvc + m2[rg]);
      float vr = x + xx * (mrc + m3[rg]);
      size_t off = (size_t)bt * C_ + c;
      XW[off] = io<u16>::cvt1(vw);
      XV[off] = io<u16>::cvt1(vv);
      RKI[off] = (u32)io<u16>::cvt1(vr) | ((u32)io<u16>::cvt1(vk) << 16);
    }
  }
}

// ---------------- K2 (fp32 legacy): four separate outputs ----------------
static __global__ __launch_bounds__(256) void k2_mix_f32(
    const float* __restrict__ hidden, const float* __restrict__ attn_x,
    const float* __restrict__ P, const float* __restrict__ W2,
    const float* __restrict__ maa_w, const float* __restrict__ maa_k,
    const float* __restrict__ maa_v, const float* __restrict__ maa_r,
    float* __restrict__ XW, float* __restrict__ XK,
    float* __restrict__ XV, float* __restrict__ XR) {
  int cb = blockIdx.x & 7;
  int tb = blockIdx.x >> 3;
  int c = cb * 256 + threadIdx.x;
  int bt0 = tb * 16;
  float xv_[16], xx_[16];
#pragma unroll
  for (int tk = 0; tk < 16; ++tk) {
    int bt = bt0 + tk;
    float x = hidden[(size_t)bt * C_ + c];
    int t = bt & (T_ - 1);
    int b = bt >> 12;
    float xp = (t == 0) ? attn_x[(size_t)b * C_ + c]
                        : hidden[(size_t)(bt - 1) * C_ + c];
    xv_[tk] = x;
    xx_[tk] = xp - x;
  }
#pragma unroll
  for (int f = 0; f < 4; ++f) {
    const float* mp = (f == 0) ? maa_w : (f == 1) ? maa_k : (f == 2) ? maa_v : maa_r;
    float* op       = (f == 0) ? XW    : (f == 1) ? XK    : (f == 2) ? XV    : XR;
    float w2r[32];
#pragma unroll
    for (int k = 0; k < 32; ++k) w2r[k] = W2[(size_t)(f * 32 + k) * C_ + c];
    float mf = mp[c];
    for (int tk = 0; tk < 16; ++tk) {
      const float4* p4 = (const float4*)(P + (size_t)(bt0 + tk) * 128 + f * 32);
      float a0 = 0.f, a1 = 0.f, a2 = 0.f, a3 = 0.f;
#pragma unroll
      for (int q = 0; q < 8; ++q) {
        float4 pv = p4[q];
        a0 = fmaf(pv.x, w2r[4 * q + 0], a0);
        a1 = fmaf(pv.y, w2r[4 * q + 1], a1);
        a2 = fmaf(pv.z, w2r[4 * q + 2], a2);
        a3 = fmaf(pv.w, w2r[4 * q + 3], a3);
      }
      float acc = (a0 + a1) + (a2 + a3);
      op[(size_t)(bt0 + tk) * C_ + c] = xv_[tk] + xx_[tk] * (mf + acc);
    }
  }
}

// ---------------- K3 (bf16, MFMA): D1 = tanh(XW @ DW1), D1 stored bf16 ----------------
static __global__ __launch_bounds__(256) void k3_mfma(
    const u16* __restrict__ XW, const u16* __restrict__ DW1T,
    u16* __restrict__ D1b) {
  int tid = threadIdx.x;
  int lane = tid & 63, wv = tid >> 6;
  int bt0 = blockIdx.x * 16;
  int j0 = wv * 16;
  int row = lane & 15, kg = lane >> 4;
  const u16* xa = XW   + (size_t)(bt0 + row) * C_ + kg * 8;
  const u16* bp = DW1T + (size_t)(j0 + row) * C_ + kg * 8;
  f32x4 acc = {0.f, 0.f, 0.f, 0.f};
#pragma unroll 8
  for (int c0 = 0; c0 < C_; c0 += 32) {
    bf16x8 a = *(const bf16x8*)(xa + c0);
    bf16x8 b = *(const bf16x8*)(bp + c0);
    acc = __builtin_amdgcn_mfma_f32_16x16x32_bf16(a, b, acc, 0, 0, 0);
  }
  int orow = bt0 + kg * 4;
#pragma unroll
  for (int rg = 0; rg < 4; ++rg)
    D1b[(size_t)(orow + rg) * 64 + j0 + row] = io<u16>::cvt1(tanhf(acc[rg]));
}

// ---------------- K3 (fp32 legacy) ----------------
template <typename ST>
static __global__ __launch_bounds__(256) void k3_d1(
    const ST* __restrict__ XW, const float* __restrict__ DW1,
    float* __restrict__ D1) {
  __shared__ float w1s[2][64 * 64];
  int tid = threadIdx.x;
  int lane = tid & 63;
  int wv = tid >> 6;
  int bt0 = blockIdx.x * 16 + wv * 4;
  float acc[4];
#pragma unroll
  for (int tk = 0; tk < 4; ++tk) acc[tk] = 0.f;

#pragma unroll
  for (int q = 0; q < 4; ++q) {
    int idx = q * 256 + tid;
    int cc = idx >> 4;
    int j4 = (idx & 15) * 4;
    *(float4*)&w1s[0][cc * 64 + j4] = *(const float4*)&DW1[(size_t)cc * 64 + j4];
  }
  __syncthreads();

#pragma unroll 1
  for (int ch = 0; ch < 32; ++ch) {
    int c0 = ch * 64;
    int buf = ch & 1;
    float z0 = io<ST>::ld(XW + (size_t)(bt0 + 0) * C_ + c0 + lane);
    float z1 = io<ST>::ld(XW + (size_t)(bt0 + 1) * C_ + c0 + lane);
    float z2 = io<ST>::ld(XW + (size_t)(bt0 + 2) * C_ + c0 + lane);
    float z3 = io<ST>::ld(XW + (size_t)(bt0 + 3) * C_ + c0 + lane);
    if (ch + 1 < 32) {
#pragma unroll
      for (int q = 0; q < 4; ++q) {
        int idx = q * 256 + tid;
        int cc = idx >> 4;
        int j4 = (idx & 15) * 4;
        *(float4*)&w1s[buf ^ 1][cc * 64 + j4] =
            *(const float4*)&DW1[(size_t)(c0 + 64 + cc) * 64 + j4];
      }
    }
#pragma unroll
    for (int l = 0; l < 64; ++l) {
      float wa = w1s[buf][l * 64 + lane];
      acc[0] = fmaf(bcast(z0, l), wa, acc[0]);
      acc[1] = fmaf(bcast(z1, l), wa, acc[1]);
      acc[2] = fmaf(bcast(z2, l), wa, acc[2]);
      acc[3] = fmaf(bcast(z3, l), wa, acc[3]);
    }
    __syncthreads();
  }
#pragma unroll
  for (int tk = 0; tk < 4; ++tk)
    D1[(size_t)(bt0 + tk) * 64 + lane] = tanhf(acc[tk]);
}

// ---------------- K4 (bf16, MFMA): DEC = exp(-exp(td + D1 @ DW2)) ----------------
static __global__ __launch_bounds__(256) void k4_mfma(
    const u16* __restrict__ D1b, const u16* __restrict__ DW2T,
    const float* __restrict__ td, u16* __restrict__ DEC) {
  int tid = threadIdx.x;
  int lane = tid & 63, wv = tid >> 6;
  int bt0 = blockIdx.x * 16;
  int row = lane & 15, kg = lane >> 4;
  const u16* da = D1b + (size_t)(bt0 + row) * 64 + kg * 8;
  bf16x8 a0 = *(const bf16x8*)(da);
  bf16x8 a1 = *(const bf16x8*)(da + 32);
#pragma unroll 1
  for (int it = 0; it < 32; ++it) {
    int c = it * 64 + wv * 16 + row;
    const u16* wb = DW2T + (size_t)c * 64 + kg * 8;
    bf16x8 b0 = *(const bf16x8*)(wb);
    bf16x8 b1 = *(const bf16x8*)(wb + 32);
    f32x4 acc = {0.f, 0.f, 0.f, 0.f};
    acc = __builtin_amdgcn_mfma_f32_16x16x32_bf16(a0, b0, acc, 0, 0, 0);
    acc = __builtin_amdgcn_mfma_f32_16x16x32_bf16(a1, b1, acc, 0, 0, 0);
    float tdv = td[c];
#pragma unroll
    for (int rg = 0; rg < 4; ++rg) {
      int bt = bt0 + kg * 4 + rg;
      float w = tdv + acc[rg];
      DEC[(size_t)bt * C_ + c] = io<u16>::cvt1(expf(-expf(w)));
    }
  }
}

// ---------------- K4 (fp32 legacy) ----------------
template <typename ST>
static __global__ __launch_bounds__(256) void k4_decay(
    const float* __restrict__ D1, const float* __restrict__ DW2,
    const float* __restrict__ td, ST* __restrict__ DEC) {
  int cb = blockIdx.x & 7;
  int tb = blockIdx.x >> 3;
  int c = cb * 256 + threadIdx.x;
  int bt0 = tb * 16;
  float w2r[64];
#pragma unroll
  for (int k = 0; k < 64; ++k) w2r[k] = DW2[(size_t)k * C_ + c];
  float tdv = td[c];
  for (int tk = 0; tk < 16; ++tk) {
    const float4* d4 = (const float4*)(D1 + (size_t)(bt0 + tk) * 64);
    float a0 = 0.f, a1 = 0.f, a2 = 0.f, a3 = 0.f;
#pragma unroll
    for (int q = 0; q < 16; ++q) {
      float4 dv = d4[q];
      a0 = fmaf(dv.x, w2r[4 * q + 0], a0);
      a1 = fmaf(dv.y, w2r[4 * q + 1], a1);
      a2 = fmaf(dv.z, w2r[4 * q + 2], a2);
      a3 = fmaf(dv.w, w2r[4 * q + 3], a3);
    }
    float w = tdv + (a0 + a1) + (a2 + a3);
    io<ST>::st(DEC + (size_t)(bt0 + tk) * C_ + c, expf(-expf(w)));
  }
}

// ---------------- K5 (fp32 legacy): round-0 register-broadcast version ----------------
static __global__ __launch_bounds__(256) void k5_intra_f32(
    float* XRQ,
    const float* __restrict__ XK, const float* __restrict__ XV,
    const float* __restrict__ DEC, const float* __restrict__ faaaa,
    float* __restrict__ UC, float* __restrict__ DCp, float* __restrict__ Y) {
  int m = threadIdx.x & 63;
  int chunk = blockIdx.x * 4 + (threadIdx.x >> 6);
  int cc = chunk & (NC_ - 1);
  int h = (chunk >> 6) & (H_ - 1);
  int b = chunk >> 11;
  float u = faaaa[h];
  float s[64];
#pragma unroll
  for (int n = 0; n < 64; ++n) s[n] = 0.f;
  float areg = 1.f;
  size_t row = ((size_t)(b * T_ + cc * L_)) * C_ + h * N_;
  for (int t = 0; t < L_; ++t, row += C_) {
    float vm = XV[row + m];
    float wl = DEC[row + m];
    float kl = XK[row + m];
    float rl = XRQ[row + m];
    float dot = rl * kl;
#pragma unroll
    for (int mk = 32; mk >= 1; mk >>= 1) dot += __shfl_xor(dot, mk, 64);
    float y0 = u * vm * dot, y1 = 0.f, y2 = 0.f, y3 = 0.f;
#pragma unroll
    for (int n = 0; n < 64; n += 4) {
      float rn, kn, wn;
      rn = bcast(rl, n + 0); kn = bcast(kl, n + 0); wn = bcast(wl, n + 0);
      y0 = fmaf(rn, s[n + 0], y0); s[n + 0] = fmaf(wn, s[n + 0], kn * vm);
      rn = bcast(rl, n + 1); kn = bcast(kl, n + 1); wn = bcast(wl, n + 1);
      y1 = fmaf(rn, s[n + 1], y1); s[n + 1] = fmaf(wn, s[n + 1], kn * vm);
      rn = bcast(rl, n + 2); kn = bcast(kl, n + 2); wn = bcast(wl, n + 2);
      y2 = fmaf(rn, s[n + 2], y2); s[n + 2] = fmaf(wn, s[n + 2], kn * vm);
      rn = bcast(rl, n + 3); kn = bcast(kl, n + 3); wn = bcast(wl, n + 3);
      y3 = fmaf(rn, s[n + 3], y3); s[n + 3] = fmaf(wn, s[n + 3], kn * vm);
    }
    XRQ[row + m] = rl * areg;
    areg *= wl;
    Y[row + m] = (y0 + y1) + (y2 + y3);
  }
  size_t ucb = (size_t)chunk * (N_ * N_);
#pragma unroll
  for (int n = 0; n < 64; ++n) UC[ucb + (size_t)n * 64 + m] = s[n];
  DCp[(size_t)chunk * N_ + m] = areg;
}

// ---------------- K5 (bf16 packed + clamped prefetch) — round-7 best variant ----------------
static __global__ __launch_bounds__(256) void k5_intra_bf16(
    const u32* __restrict__ RKI, u16* XVRQ,
    const u16* __restrict__ DEC, const float* __restrict__ faaaa,
    u16* __restrict__ UC, float* __restrict__ DCp, float* __restrict__ Y) {
  int m = threadIdx.x & 63;
  int chunk = blockIdx.x * 4 + (threadIdx.x >> 6);
  int cc = chunk & (NC_ - 1);
  int h = (chunk >> 6) & (H_ - 1);
  int b = chunk >> 11;
  float u = faaaa[h];
  float s[64];
#pragma unroll
  for (int n = 0; n < 64; ++n) s[n] = 0.f;
  float areg = 1.f;
  size_t row = ((size_t)(b * T_ + cc * L_)) * C_ + h * N_;
  u32 nrki = RKI[row + m];
  float nvm = io<u16>::ld(XVRQ + row + m);
  float nwl = io<u16>::ld(DEC + row + m);
  u32 nwpk = ((const u32*)(DEC + row))[m & 31];
#pragma unroll 1
  for (int t = 0; t < L_; ++t, row += C_) {
    u32 rki = nrki;
    float vm = nvm;
    float wl = nwl;
    u32 wpk = nwpk;
    size_t nx = (t + 1 < L_) ? row + C_ : row;   // clamped prefetch (last iter: dummy)
    nrki = RKI[nx + m];
    nvm = io<u16>::ld(XVRQ + nx + m);
    nwl = io<u16>::ld(DEC + nx + m);
    nwpk = ((const u32*)(DEC + nx))[m & 31];
    float rl = bflo(rki), kl = bfhi(rki);
    float dot = rl * kl;
#pragma unroll
    for (int mk = 32; mk >= 1; mk >>= 1) dot += __shfl_xor(dot, mk, 64);
    float y0 = u * vm * dot, y1 = 0.f, y2 = 0.f, y3 = 0.f;
#pragma unroll
    for (int i = 0; i < 32; ++i) {
      u32 rk0 = bcast_u(rki, 2 * i);
      u32 rk1 = bcast_u(rki, 2 * i + 1);
      u32 wp  = bcast_u(wpk, i);
      float r0 = bflo(rk0), k0 = bfhi(rk0);
      float r1 = bflo(rk1), k1 = bfhi(rk1);
      float w0 = bflo(wp),  w1 = bfhi(wp);
      int n = 2 * i;
      if (i & 1) {
        y2 = fmaf(r0, s[n], y2);     s[n]     = fmaf(w0, s[n],     k0 * vm);
        y3 = fmaf(r1, s[n + 1], y3); s[n + 1] = fmaf(w1, s[n + 1], k1 * vm);
      } else {
        y0 = fmaf(r0, s[n], y0);     s[n]     = fmaf(w0, s[n],     k0 * vm);
        y1 = fmaf(r1, s[n + 1], y1); s[n + 1] = fmaf(w1, s[n + 1], k1 * vm);
      }
    }
    io<u16>::st(XVRQ + row + m, rl * areg);   // RQ = r * cumdecay (pre-step)
    areg *= wl;
    Y[row + m] = (y0 + y1) + (y2 + y3);
  }
  size_t ucb = (size_t)chunk * (N_ * N_);
#pragma unroll
  for (int n = 0; n < 64; ++n) io<u16>::st(UC + ucb + (size_t)n * 64 + m, s[n]);
  DCp[(size_t)chunk * N_ + m] = areg;
}

// ---------------- K6 (fp32 legacy): inter-chunk state scan ----------------
template <typename ST>
static __global__ __launch_bounds__(256) void k6_scan(
    const float* __restrict__ attn_kv, ST* __restrict__ UC,
    const float* __restrict__ DCp) {
  int msel = blockIdx.x & 3;
  int bh = blockIdx.x >> 2;
  int ml = threadIdx.x & 15;
  int n0 = threadIdx.x >> 4;
  int m = msel * 16 + ml;
  float s[4];
#pragma unroll
  for (int i = 0; i < 4; ++i) {
    int n = n0 + 16 * i;
    s[i] = attn_kv[((size_t)bh * N_ + n) * N_ + m];
  }
  for (int c = 0; c < NC_; ++c) {
    size_t cb = (size_t)bh * NC_ + c;
#pragma unroll
    for (int i = 0; i < 4; ++i) {
      int n = n0 + 16 * i;
      size_t idx = (cb * (size_t)(N_ * N_)) + (size_t)n * 64 + m;
      float uc = io<ST>::ld(UC + idx);
      float dc = DCp[cb * N_ + n];
      io<ST>::st(UC + idx, s[i]);
      s[i] = fmaf(dc, s[i], uc);
    }
  }
}

// ---------------- K6 (bf16, paired): dword scans with prefetch ----------------
static __global__ __launch_bounds__(256) void k6_scan_v2(
    const float* __restrict__ attn_kv, u16* __restrict__ UC,
    const float* __restrict__ DCp) {
  int bh = blockIdx.x >> 3;
  int sub = blockIdx.x & 7;
  int tid = threadIdx.x;
  int n = sub * 8 + (tid >> 5);
  int mp = tid & 31;                       // m = 2*mp, 2*mp+1
  float2 s = *(const float2*)(attn_kv + ((size_t)bh * N_ + n) * N_ + 2 * mp);
  u32* UCd = (u32*)UC;
  size_t base = ((size_t)bh * NC_) * 2048 + (size_t)n * 32 + mp;
  u32 nuc = UCd[base];
  float ndc = DCp[((size_t)bh * NC_) * N_ + n];
#pragma unroll 1
  for (int c = 0; c < NC_; ++c) {
    u32 uc = nuc;
    float dc = ndc;
    size_t idx = base + (size_t)c * 2048;
    if (c + 1 < NC_) {
      nuc = UCd[idx + 2048];
      ndc = DCp[((size_t)bh * NC_ + c + 1) * N_ + n];
    }
    u32 pk = (u32)io<u16>::cvt1(s.x) | ((u32)io<u16>::cvt1(s.y) << 16);
    UCd[idx] = pk;                          // state at chunk start (for k7)
    s.x = fmaf(dc, s.x, bflo(uc));
    s.y = fmaf(dc, s.y, bfhi(uc));
  }
}

// ---------------- K7 (fp32 legacy) ----------------
static __global__ __launch_bounds__(256) void k7_state_f32(
    const float* __restrict__ RQ, const float* __restrict__ UC,
    float* __restrict__ Y) {
  int m = threadIdx.x & 63;
  int chunk = blockIdx.x * 4 + (threadIdx.x >> 6);
  int cc = chunk & (NC_ - 1);
  int h = (chunk >> 6) & (H_ - 1);
  int b = chunk >> 11;
  float sc[64];
  size_t ucb = (size_t)chunk * (N_ * N_);
#pragma unroll
  for (int n = 0; n < 64; ++n) sc[n] = UC[ucb + (size_t)n * 64 + m];
  size_t row = ((size_t)(b * T_ + cc * L_)) * C_ + h * N_;
  for (int t = 0; t < L_; ++t, row += C_) {
    float ql = RQ[row + m];
    float y0 = Y[row + m], y1 = 0.f, y2 = 0.f, y3 = 0.f;
#pragma unroll
    for (int n = 0; n < 64; n += 4) {
      y0 = fmaf(bcast(ql, n + 0), sc[n + 0], y0);
      y1 = fmaf(bcast(ql, n + 1), sc[n + 1], y1);
      y2 = fmaf(bcast(ql, n + 2), sc[n + 2], y2);
      y3 = fmaf(bcast(ql, n + 3), sc[n + 3], y3);
    }
    Y[row + m] = (y0 + y1) + (y2 + y3);
  }
}

// ---------------- K7 (bf16, MFMA): Y += RQ(64x64) @ S0(64x64) per chunk ----------------
static __global__ __launch_bounds__(256) void k7_mfma(
    const u16* __restrict__ RQ, const u16* __restrict__ UC,
    float* __restrict__ Y) {
  __shared__ u16 st[64][64];   // st[m][n ^ ((m&7)<<3)] = S0[n][m]
  int tid = threadIdx.x;
  int chunk = blockIdx.x;
  int cc = chunk & (NC_ - 1);
  int h = (chunk >> 6) & (H_ - 1);
  int b = chunk >> 11;
  const u16* S0 = UC + (size_t)chunk * (N_ * N_);
  {
    int n = tid >> 2;
    int m0 = (tid & 3) << 4;
#pragma unroll
    for (int j = 0; j < 16; ++j) {
      int m = m0 + j;
      st[m][n ^ ((m & 7) << 3)] = S0[n * 64 + m];
    }
  }
  __syncthreads();
  int lane = tid & 63;
  int wv = tid >> 6;
  int trow = lane & 15;
  int kg = lane >> 4;
  int t0 = wv << 4;
  size_t arow = ((size_t)(b * T_ + cc * L_ + t0 + trow)) * C_ + h * N_;
  bf16x8 a0 = *(const bf16x8*)(RQ + arow + kg * 8);
  bf16x8 a1 = *(const bf16x8*)(RQ + arow + 32 + kg * 8);
#pragma unroll
  for (int ct = 0; ct < 4; ++ct) {
    int col = ct * 16 + trow;
    int sw = (col & 7) << 3;
    bf16x8 b0 = *(const bf16x8*)&st[col][(kg * 8) ^ sw];
    bf16x8 b1 = *(const bf16x8*)&st[col][(32 + kg * 8) ^ sw];
    f32x4 c = {0.f, 0.f, 0.f, 0.f};
    c = __builtin_amdgcn_mfma_f32_16x16x32_bf16(a0, b0, c, 0, 0, 0);
    c = __builtin_amdgcn_mfma_f32_16x16x32_bf16(a1, b1, c, 0, 0, 0);
    size_t ybase = ((size_t)(b * T_ + cc * L_ + t0 + kg * 4)) * C_ + h * N_ + ct * 16 + trow;
#pragma unroll
    for (int rg = 0; rg < 4; ++rg)
      Y[ybase + (size_t)rg * C_] += c[rg];
  }
}

// ---------------- host ----------------
static void run_f32(void* const* d_in, void* d_out, void* d_ws, hipStream_t stream) {
  const float* hidden = (const float*)d_in[0];
  const float* attn_x = (const float*)d_in[1];
  const float* attn_kv = (const float*)d_in[2];
  const float* maa_x = (const float*)d_in[4];
  const float* maa_w = (const float*)d_in[5];
  const float* maa_k = (const float*)d_in[6];
  const float* maa_v = (const float*)d_in[7];
  const float* maa_r = (const float*)d_in[8];
  const float* W1 = (const float*)d_in[10];
  const float* W2 = (const float*)d_in[11];
  const float* tdec = (const float*)d_in[12];
  const float* DW1 = (const float*)d_in[13];
  const float* DW2 = (const float*)d_in[14];
  const float* faaaa = (const float*)d_in[15];

  const size_t BIG = (size_t)BT_ * C_;
  char* p = (char*)d_ws;
  float* A   = (float*)p; p += BIG * 4;
  float* XK  = (float*)p; p += BIG * 4;
  float* XV  = (float*)p; p += BIG * 4;
  float* XRQ = (float*)p; p += BIG * 4;
  float* UC  = (float*)p; p += BIG * 4;
  float* P   = (float*)p; p += (size_t)BT_ * 128 * 4;
  float* D1  = (float*)p; p += (size_t)BT_ * 64 * 4;
  float* DCp = (float*)p;
  float* Y = (float*)d_out;

  k0_z<float>    <<<16384, 256, 0, stream>>>(hidden, attn_x, maa_x, A);
  k1_p<float>    <<<BT_ / 16, 256, 0, stream>>>(A, W1, P);
  k2_mix_f32     <<<(BT_ / 16) * 8, 256, 0, stream>>>(hidden, attn_x, P, W2,
                                                      maa_w, maa_k, maa_v, maa_r,
                                                      A, XK, XV, XRQ);
  k3_d1<float>   <<<BT_ / 16, 256, 0, stream>>>(A, DW1, D1);
  k4_decay<float><<<(BT_ / 16) * 8, 256, 0, stream>>>(D1, DW2, tdec, A);
  k5_intra_f32   <<<B_ * H_ * NC_ / 4, 256, 0, stream>>>(XRQ, XK, XV, A, faaaa,
                                                         UC, DCp, Y);
  k6_scan<float> <<<B_ * H_ * 4, 256, 0, stream>>>(attn_kv, UC, DCp);
  k7_state_f32   <<<B_ * H_ * NC_ / 4, 256, 0, stream>>>(XRQ, UC, Y);
}

static void run_bf16(void* const* d_in, void* d_out, void* d_ws, hipStream_t stream) {
  const float* hidden = (const float*)d_in[0];
  const float* attn_x = (const float*)d_in[1];
  const float* attn_kv = (const float*)d_in[2];
  const float* maa_x = (const float*)d_in[4];
  const float* maa_w = (const float*)d_in[5];
  const float* maa_k = (const float*)d_in[6];
  const float* maa_v = (const float*)d_in[7];
  const float* maa_r = (const float*)d_in[8];
  const float* W1 = (const float*)d_in[10];
  const float* W2 = (const float*)d_in[11];
  const float* tdec = (const float*)d_in[12];
  const float* DW1 = (const float*)d_in[13];
  const float* DW2 = (const float*)d_in[14];
  const float* faaaa = (const float*)d_in[15];

  const size_t BIG = (size_t)BT_ * C_;
  char* p = (char*)d_ws;
  u16* A    = (u16*)p; p += BIG * 2;         // Z -> XW -> DEC
  u32* RKI  = (u32*)p; p += BIG * 4;         // (k<<16)|r packed
  u16* XVRQ = (u16*)p; p += BIG * 2;         // XV, overwritten by RQ in k5
  u16* UC   = (u16*)p; p += BIG * 2;
  char* Pr  = p; p += (size_t)BT_ * 128 * 4; // 4 MB region: Pb(2M) + W2T(0.5M) + DW2T(0.25M)
  char* D1r = p; p += (size_t)BT_ * 64 * 4;  // 2 MB region: W1T(0.5M) then D1b(1M)
  float* DCp = (float*)p;                    // 1 MB region: DW1T(0.25M) then DCp(1M)
  float* Y = (float*)d_out;

  u16* Pb   = (u16*)Pr;
  u16* W2T  = (u16*)(Pr + (size_t)BT_ * 128 * 2);
  u16* DW2T = (u16*)(Pr + (size_t)BT_ * 128 * 2 + 128 * 2048 * 2);
  u16* W1T  = (u16*)D1r;
  u16* D1b  = (u16*)D1r;                     // overwrites W1T after k1 is done
  u16* DW1T = (u16*)DCp;                     // overwritten by DCp in k5 (after k3)

  wt_prep      <<<192, 256, 0, stream>>>(W1, DW1, W2, DW2, W1T, DW1T, W2T, DW2T);
  k0_z<u16>    <<<16384, 256, 0, stream>>>(hidden, attn_x, maa_x, A);
  k1_mfma      <<<BT_ / 16, 256, 0, stream>>>(A /*Z*/, W1T, Pb);
  k2_mfma      <<<BT_ / 16, 256, 0, stream>>>(hidden, attn_x, Pb, W2T,
                                              maa_w, maa_k, maa_v, maa_r,
                                              A /*XW*/, RKI, XVRQ /*XV*/);
  k3_mfma      <<<BT_ / 16, 256, 0, stream>>>(A /*XW*/, DW1T, D1b);
  k4_mfma      <<<BT_ / 16, 256, 0, stream>>>(D1b, DW2T, tdec, A /*DEC*/);
  k5_intra_bf16<<<B_ * H_ * NC_ / 4, 256, 0, stream>>>(RKI, XVRQ, A /*DEC*/, faaaa,
                                                       UC, DCp, Y);
  k6_scan_v2   <<<B_ * H_ * 8, 256, 0, stream>>>(attn_kv, UC, DCp);
  k7_mfma      <<<B_ * H_ * NC_, 256, 0, stream>>>(XVRQ /*RQ*/, UC, Y);
}

extern "C" void kernel_launch(void* const* d_in, const int* in_sizes, int n_in,
                              void* d_out, int out_size, void* d_ws, size_t ws_size,
                              hipStream_t stream) {
  const size_t BIG = (size_t)BT_ * C_;
  const size_t small = (size_t)BT_ * 128 * 4 + (size_t)BT_ * 64 * 4 +
                       (size_t)B_ * H_ * NC_ * N_ * 4;
  const size_t need_f32 = BIG * 4 * 5 + small;   // ~343 MB
  if (ws_size >= need_f32)
    run_f32(d_in, d_out, d_ws, stream);
  else
    run_bf16(d_in, d_out, d_ws, stream);         // bf16 storage + packed RKI, ~176 MB
}